// Round 9
// baseline (67.699 us; speedup 1.0000x reference)
//
#include <hip/hip_runtime.h>
#include <stdint.h>

#define BTOT 4096
#define DD   256
#define SS   32
#define KKN  32
#define NGEMM 528              // 32*33/2 triangular tiles
#define NBLK  (NGEMM * 3)      // 1584: 1-in-3 gemm, rest simdiv (1056, 1024 used)

typedef unsigned short u16;
using f32x4  = __attribute__((ext_vector_type(4))) float;
using bf16x8 = __attribute__((ext_vector_type(8))) short;

__device__ __forceinline__ u16 f2bf(float f) {
    uint32_t u = __builtin_bit_cast(uint32_t, f);
    u = (u + 0x7FFFu + ((u >> 16) & 1u)) >> 16;
    return (u16)u;
}
__device__ __forceinline__ float bf2f(u16 h) {
    uint32_t u = ((uint32_t)h) << 16;
    return __builtin_bit_cast(float, u);
}

// ---- fat kernel: bid%3==2 -> triangular GEMM tile; else -> simdiv rows ----
// GEMM reg-stages fp32 E -> bf16 LDS in-register (no cast kernel, no ebf
// buffer); conversion VALU hides under the streaming plateau. simdiv is
// LDS-free/register-direct so gemm's 20KB static LDS doesn't displace it.
__global__ __launch_bounds__(256) void fat_kernel(
    const float* __restrict__ E, const float* __restrict__ Sim, const float* __restrict__ Div,
    const int* __restrict__ labels,
    float* __restrict__ gden, float* __restrict__ gnum, float* __restrict__ sdpart)
{
    __shared__ u16 As[128 * 32];
    __shared__ u16 Bs[128 * 32];
    __shared__ float rbuf[2][2][128];
    __shared__ float cbuf[2][2][128];

    int bid  = blockIdx.x;
    int t    = threadIdx.x;
    int w    = t >> 6;
    int lane = t & 63;

    if (bid % 3 == 2) {
        // ================= GEMM path =================
        int g = bid / 3;
        int R = (int)((65.0f - sqrtf(4225.0f - 8.0f * (float)g)) * 0.5f);
        while (R > 0 && R * (65 - R) / 2 > g) --R;
        while ((R + 1) * (64 - R) / 2 <= g) ++R;
        int C = R + (g - R * (65 - R) / 2);

        int brow = R * 128, bcol = C * 128;
        int wr = w >> 1, wc = w & 1;
        int r16 = lane & 15, hi = lane >> 4;
        int kq = hi * 8;

        f32x4 acc[4][4] = {};

        for (int kt = 0; kt < DD / 32; ++kt) {
            int k0 = kt * 32;
            // reg-stage: fp32 -> bf16 -> LDS (identical rounding to old cast path)
            #pragma unroll
            for (int it = 0; it < 2; ++it) {
                int c   = t + 256 * it;
                int row = c >> 2;
                int col = (c & 3) * 8;
                const float* ga = &E[(size_t)(brow + row) * DD + k0 + col];
                const float* gb = &E[(size_t)(bcol + row) * DD + k0 + col];
                float4 a0 = *(const float4*)ga;
                float4 a1 = *(const float4*)(ga + 4);
                float4 b0 = *(const float4*)gb;
                float4 b1 = *(const float4*)(gb + 4);
                uint4 pa, pb;
                pa.x = (uint32_t)f2bf(a0.x) | ((uint32_t)f2bf(a0.y) << 16);
                pa.y = (uint32_t)f2bf(a0.z) | ((uint32_t)f2bf(a0.w) << 16);
                pa.z = (uint32_t)f2bf(a1.x) | ((uint32_t)f2bf(a1.y) << 16);
                pa.w = (uint32_t)f2bf(a1.z) | ((uint32_t)f2bf(a1.w) << 16);
                pb.x = (uint32_t)f2bf(b0.x) | ((uint32_t)f2bf(b0.y) << 16);
                pb.y = (uint32_t)f2bf(b0.z) | ((uint32_t)f2bf(b0.w) << 16);
                pb.z = (uint32_t)f2bf(b1.x) | ((uint32_t)f2bf(b1.y) << 16);
                pb.w = (uint32_t)f2bf(b1.z) | ((uint32_t)f2bf(b1.w) << 16);
                *(uint4*)&As[c * 8] = pa;
                *(uint4*)&Bs[c * 8] = pb;
            }
            __syncthreads();

            bf16x8 af[4], bfr[4];
            #pragma unroll
            for (int m = 0; m < 4; ++m)
                af[m] = *(const bf16x8*)&As[(wr * 64 + m * 16 + r16) * 32 + kq];
            #pragma unroll
            for (int n = 0; n < 4; ++n)
                bfr[n] = *(const bf16x8*)&Bs[(wc * 64 + n * 16 + r16) * 32 + kq];
            #pragma unroll
            for (int m = 0; m < 4; ++m)
                #pragma unroll
                for (int n = 0; n < 4; ++n)
                    acc[m][n] = __builtin_amdgcn_mfma_f32_16x16x32_bf16(af[m], bfr[n], acc[m][n], 0, 0, 0);
            __syncthreads();
        }

        bool offdiag = (C != R);

        float malf[4];
        #pragma unroll
        for (int n = 0; n < 4; ++n)
            malf[n] = (float)labels[bcol + wc * 64 + n * 16 + r16];
        float malr[16];
        #pragma unroll
        for (int m = 0; m < 4; ++m)
            #pragma unroll
            for (int r = 0; r < 4; ++r)
                malr[m * 4 + r] = (float)labels[brow + wr * 64 + m * 16 + hi * 4 + r];

        float cd[4] = {0.f, 0.f, 0.f, 0.f}, cn[4] = {0.f, 0.f, 0.f, 0.f};

        #pragma unroll
        for (int m = 0; m < 4; ++m) {
            #pragma unroll
            for (int r = 0; r < 4; ++r) {
                float pe = 0.f, pn = 0.f;
                #pragma unroll
                for (int n = 0; n < 4; ++n) {
                    float v  = acc[m][n][r];
                    float ex = __expf(v);
                    pe += ex;
                    pn += malf[n] * v;
                    cd[n] += ex;
                    cn[n] += malr[m * 4 + r] * v;
                }
                #pragma unroll
                for (int s = 1; s < 16; s <<= 1) {
                    pe += __shfl_xor(pe, s, 64);
                    pn += __shfl_xor(pn, s, 64);
                }
                if (r16 == 0) {
                    int rl = wr * 64 + m * 16 + hi * 4 + r;
                    rbuf[0][wc][rl] = pe;
                    rbuf[1][wc][rl] = pn;
                }
            }
        }

        if (offdiag) {
            #pragma unroll
            for (int n = 0; n < 4; ++n) {
                cd[n] += __shfl_xor(cd[n], 16, 64);
                cd[n] += __shfl_xor(cd[n], 32, 64);
                cn[n] += __shfl_xor(cn[n], 16, 64);
                cn[n] += __shfl_xor(cn[n], 32, 64);
                if (lane < 16) {
                    int cl = wc * 64 + n * 16 + lane;
                    cbuf[0][wr][cl] = cd[n];
                    cbuf[1][wr][cl] = cn[n];
                }
            }
        }
        __syncthreads();

        if (t < 128) {
            int i = brow + t;
            gden[(size_t)i * 32 + C] = rbuf[0][0][t] + rbuf[0][1][t];
            gnum[(size_t)i * 32 + C] = rbuf[1][0][t] + rbuf[1][1][t];
        } else if (offdiag) {
            int tt = t - 128;
            int j = bcol + tt;
            gden[(size_t)j * 32 + R] = cbuf[0][0][tt] + cbuf[0][1][tt];
            gnum[(size_t)j * 32 + R] = cbuf[1][0][tt] + cbuf[1][1][tt];
        }
    } else {
        // ================= simdiv path (register-direct) =================
        int sid = bid - bid / 3;            // 0..1055 over non-gemm bids
        if (sid >= BTOT / 4) return;
        int i = sid * 4 + w;                // one wave per row
        int g = lane >> 4, sub = lane & 15;

        const char* Eb = (const char*)(E + (size_t)i * DD);
        float4 e0 = *(const float4*)(Eb + 0 * 256 + sub * 16);
        float4 e1 = *(const float4*)(Eb + 1 * 256 + sub * 16);
        float4 e2 = *(const float4*)(Eb + 2 * 256 + sub * 16);
        float4 e3 = *(const float4*)(Eb + 3 * 256 + sub * 16);

        const char* Sb = (const char*)(Sim + (size_t)i * SS * DD) + g * 1024 + sub * 16;
        const char* Db = (const char*)(Div + (size_t)i * KKN * DD) + g * 1024 + sub * 16;

        float4 buf[4][4];
        float accs = 0.f, acce = 0.f;

#define ISSUE(SET)                                                                  \
    {                                                                               \
        const char* b_ = ((SET) < 8) ? (Sb + (SET) * 4096) : (Db + ((SET) - 8) * 4096); \
        buf[(SET) & 3][0] = *(const float4*)(b_ + 0);                               \
        buf[(SET) & 3][1] = *(const float4*)(b_ + 256);                             \
        buf[(SET) & 3][2] = *(const float4*)(b_ + 512);                             \
        buf[(SET) & 3][3] = *(const float4*)(b_ + 768);                             \
    }

#define COMPUTE(SET)                                                                \
    {                                                                               \
        float4 s0 = buf[(SET) & 3][0], s1 = buf[(SET) & 3][1];                      \
        float4 s2 = buf[(SET) & 3][2], s3 = buf[(SET) & 3][3];                      \
        float d = e0.x * s0.x + e0.y * s0.y + e0.z * s0.z + e0.w * s0.w             \
                + e1.x * s1.x + e1.y * s1.y + e1.z * s1.z + e1.w * s1.w             \
                + e2.x * s2.x + e2.y * s2.y + e2.z * s2.z + e2.w * s2.w             \
                + e3.x * s3.x + e3.y * s3.y + e3.z * s3.z + e3.w * s3.w;            \
        d += __shfl_xor(d, 1, 64);                                                  \
        d += __shfl_xor(d, 2, 64);                                                  \
        d += __shfl_xor(d, 4, 64);                                                  \
        d += __shfl_xor(d, 8, 64);                                                  \
        accs += d;                                                                  \
        acce += __expf(d);                                                          \
    }

        ISSUE(0) ISSUE(1) ISSUE(2) ISSUE(3)
        COMPUTE(0)  ISSUE(4)
        COMPUTE(1)  ISSUE(5)
        COMPUTE(2)  ISSUE(6)
        COMPUTE(3)  ISSUE(7)
        COMPUTE(4)  ISSUE(8)
        COMPUTE(5)  ISSUE(9)
        COMPUTE(6)  ISSUE(10)
        COMPUTE(7)  ISSUE(11)
        COMPUTE(8)  ISSUE(12)
        COMPUTE(9)  ISSUE(13)
        COMPUTE(10) ISSUE(14)
        COMPUTE(11) ISSUE(15)
        COMPUTE(12)
        COMPUTE(13)
        COMPUTE(14)
        COMPUTE(15)
#undef ISSUE
#undef COMPUTE

        accs += __shfl_xor(accs, 16, 64);
        accs += __shfl_xor(accs, 32, 64);
        acce += __shfl_xor(acce, 16, 64);
        acce += __shfl_xor(acce, 32, 64);

        // self-dot (bf16-rounded, matches MFMA diagonal)
        float sd = 0.f;
        {
            float c;
            c = bf2f(f2bf(e0.x)); sd += c * c;  c = bf2f(f2bf(e0.y)); sd += c * c;
            c = bf2f(f2bf(e0.z)); sd += c * c;  c = bf2f(f2bf(e0.w)); sd += c * c;
            c = bf2f(f2bf(e1.x)); sd += c * c;  c = bf2f(f2bf(e1.y)); sd += c * c;
            c = bf2f(f2bf(e1.z)); sd += c * c;  c = bf2f(f2bf(e1.w)); sd += c * c;
            c = bf2f(f2bf(e2.x)); sd += c * c;  c = bf2f(f2bf(e2.y)); sd += c * c;
            c = bf2f(f2bf(e2.z)); sd += c * c;  c = bf2f(f2bf(e2.w)); sd += c * c;
            c = bf2f(f2bf(e3.x)); sd += c * c;  c = bf2f(f2bf(e3.y)); sd += c * c;
            c = bf2f(f2bf(e3.z)); sd += c * c;  c = bf2f(f2bf(e3.w)); sd += c * c;
        }
        sd += __shfl_xor(sd, 1, 64);
        sd += __shfl_xor(sd, 2, 64);
        sd += __shfl_xor(sd, 4, 64);
        sd += __shfl_xor(sd, 8, 64);

        if (lane == 0) {
            float4 o; o.x = accs; o.y = acce; o.z = sd; o.w = 0.f;
            *(float4*)(sdpart + (size_t)i * 4) = o;
        }
    }
}

// ---- kernel 3: per-row fold (32 gemm partials + simdiv partials + self-term) ----
__global__ __launch_bounds__(128) void reduce1_kernel(
    const int* __restrict__ labels, const float* __restrict__ gden,
    const float* __restrict__ gnum, const float* __restrict__ sdpart,
    float* __restrict__ part)
{
    __shared__ float sA[128], sB[128];
    __shared__ int   sC[128];
    int p = blockIdx.x, t = threadIdx.x;
    int i = p * 128 + t;

    const float4* dr = reinterpret_cast<const float4*>(gden + (size_t)i * 32);
    const float4* nr = reinterpret_cast<const float4*>(gnum + (size_t)i * 32);
    float4 sp = *(const float4*)(sdpart + (size_t)i * 4);

    float num = sp.x;
    float den = sp.y;
    float sdv = sp.z;
    int lab = labels[i];
    den -= __expf(sdv);           // remove j==i from denominator
    num -= lab ? sdv : 0.f;       // remove j==i from numerator if mal[i]

    #pragma unroll
    for (int c = 0; c < 8; ++c) {
        float4 a = dr[c]; den += a.x + a.y + a.z + a.w;
        float4 b = nr[c]; num += b.x + b.y + b.z + b.w;
    }
    sA[t] = lab ? __logf(den) : 0.f;
    sB[t] = lab ? num : 0.f;
    sC[t] = lab;
    __syncthreads();
    for (int s = 64; s > 0; s >>= 1) {
        if (t < s) { sA[t] += sA[t + s]; sB[t] += sB[t + s]; sC[t] += sC[t + s]; }
        __syncthreads();
    }
    if (t == 0) {
        part[p]      = sA[0];
        part[32 + p] = sB[0];
        part[64 + p] = (float)sC[0];
    }
}

// ---- kernel 4: final scalar combine ----
__global__ __launch_bounds__(64) void final_kernel(const float* __restrict__ part,
                                                   float* __restrict__ out)
{
    int lane = threadIdx.x;
    float lg = (lane < 32) ? part[lane]      : 0.f;
    float nm = (lane < 32) ? part[32 + lane] : 0.f;
    float ml = (lane < 32) ? part[64 + lane] : 0.f;
    #pragma unroll
    for (int s = 1; s < 64; s <<= 1) {
        lg += __shfl_xor(lg, s, 64);
        nm += __shfl_xor(nm, s, 64);
        ml += __shfl_xor(ml, s, 64);
    }
    if (lane == 0) {
        float cnt = ml - 1.f + (float)(SS + KKN);
        out[0] = (lg - nm / cnt) / (float)BTOT;
    }
}

extern "C" void kernel_launch(void* const* d_in, const int* in_sizes, int n_in,
                              void* d_out, int out_size, void* d_ws, size_t ws_size,
                              hipStream_t stream) {
    const float* E   = (const float*)d_in[0];
    const float* Sim = (const float*)d_in[1];
    const float* Div = (const float*)d_in[2];
    const int* labels = (const int*)d_in[3];
    float* out = (float*)d_out;

    char* ws = (char*)d_ws;
    float* gden   = (float*)ws; ws += (size_t)BTOT * 32 * sizeof(float);
    float* gnum   = (float*)ws; ws += (size_t)BTOT * 32 * sizeof(float);
    float* sdpart = (float*)ws; ws += (size_t)BTOT * 4 * sizeof(float);
    float* part   = (float*)ws;

    fat_kernel<<<NBLK, 256, 0, stream>>>(E, Sim, Div, labels, gden, gnum, sdpart);
    reduce1_kernel<<<32, 128, 0, stream>>>(labels, gden, gnum, sdpart, part);
    final_kernel<<<1, 64, 0, stream>>>(part, out);
}

// Round 11
// 67.078 us; speedup vs baseline: 1.0093x; 1.0093x over previous
//
#include <hip/hip_runtime.h>
#include <stdint.h>

#define BTOT 4096
#define DD   256
#define SS   32
#define KKN  32
#define NGEMM 528              // 32*33/2 triangular tiles
#define NBLK  (NGEMM * 3)      // 1584: 1-in-3 gemm, rest simdiv (1056, 1024 used)

typedef unsigned short u16;
using f32x4  = __attribute__((ext_vector_type(4))) float;
using bf16x8 = __attribute__((ext_vector_type(8))) short;

__device__ __forceinline__ u16 f2bf(float f) {
    uint32_t u = __builtin_bit_cast(uint32_t, f);
    u = (u + 0x7FFFu + ((u >> 16) & 1u)) >> 16;
    return (u16)u;
}
__device__ __forceinline__ float bf2f(u16 h) {
    uint32_t u = ((uint32_t)h) << 16;
    return __builtin_bit_cast(float, u);
}

// non-temporal 16B load (gfx950 'nt' — streaming, minimal cache allocation).
// __builtin_nontemporal_load needs an ext-vector type, not HIP_vector_type.
__device__ __forceinline__ float4 ntload4(const char* p) {
    f32x4 v = __builtin_nontemporal_load((const f32x4*)p);
    return __builtin_bit_cast(float4, v);
}

// ---- kernel 0: cast embeddings fp32 -> bf16 ----
__global__ __launch_bounds__(256) void cast_kernel(const float* __restrict__ E,
                                                   u16* __restrict__ ebf) {
    int idx = blockIdx.x * 256 + threadIdx.x;
    const float4* p = reinterpret_cast<const float4*>(E) + (size_t)idx * 2;
    float4 a = p[0], b = p[1];
    uint4 o;
    o.x = (uint32_t)f2bf(a.x) | ((uint32_t)f2bf(a.y) << 16);
    o.y = (uint32_t)f2bf(a.z) | ((uint32_t)f2bf(a.w) << 16);
    o.z = (uint32_t)f2bf(b.x) | ((uint32_t)f2bf(b.y) << 16);
    o.w = (uint32_t)f2bf(b.z) | ((uint32_t)f2bf(b.w) << 16);
    reinterpret_cast<uint4*>(ebf)[idx] = o;
}

// ---- fat kernel: bid%3==2 -> triangular GEMM tile; else -> simdiv rows ----
// (round-8 verified structure; simdiv Sim/Div loads now non-temporal)
__global__ __launch_bounds__(256) void fat_kernel(
    const float* __restrict__ E, const float* __restrict__ Sim, const float* __restrict__ Div,
    const u16* __restrict__ ebf, const int* __restrict__ labels,
    float* __restrict__ gden, float* __restrict__ gnum, float* __restrict__ sdpart)
{
    __shared__ u16 As[128 * 32];
    __shared__ u16 Bs[128 * 32];
    __shared__ float rbuf[2][2][128];
    __shared__ float cbuf[2][2][128];

    int bid  = blockIdx.x;
    int t    = threadIdx.x;
    int w    = t >> 6;
    int lane = t & 63;

    if (bid % 3 == 2) {
        // ================= GEMM path (round-4 verified body) =================
        int g = bid / 3;
        int R = (int)((65.0f - sqrtf(4225.0f - 8.0f * (float)g)) * 0.5f);
        while (R > 0 && R * (65 - R) / 2 > g) --R;
        while ((R + 1) * (64 - R) / 2 <= g) ++R;
        int C = R + (g - R * (65 - R) / 2);

        int brow = R * 128, bcol = C * 128;
        int wr = w >> 1, wc = w & 1;
        int r16 = lane & 15, hi = lane >> 4;
        int kq = hi * 8;

        f32x4 acc[4][4] = {};

        for (int kt = 0; kt < DD / 32; ++kt) {
            int k0 = kt * 32;
            #pragma unroll
            for (int it = 0; it < 2; ++it) {
                int c   = t + 256 * it;
                int row = c >> 2;
                int col = (c & 3) * 8;
                const u16* ga = &ebf[(size_t)(brow + row) * DD + k0 + col];
                const u16* gb = &ebf[(size_t)(bcol + row) * DD + k0 + col];
                __builtin_amdgcn_global_load_lds(
                    (const __attribute__((address_space(1))) unsigned int*)ga,
                    (__attribute__((address_space(3))) unsigned int*)&As[c * 8], 16, 0, 0);
                __builtin_amdgcn_global_load_lds(
                    (const __attribute__((address_space(1))) unsigned int*)gb,
                    (__attribute__((address_space(3))) unsigned int*)&Bs[c * 8], 16, 0, 0);
            }
            __syncthreads();

            bf16x8 af[4], bfr[4];
            #pragma unroll
            for (int m = 0; m < 4; ++m)
                af[m] = *(const bf16x8*)&As[(wr * 64 + m * 16 + r16) * 32 + kq];
            #pragma unroll
            for (int n = 0; n < 4; ++n)
                bfr[n] = *(const bf16x8*)&Bs[(wc * 64 + n * 16 + r16) * 32 + kq];
            #pragma unroll
            for (int m = 0; m < 4; ++m)
                #pragma unroll
                for (int n = 0; n < 4; ++n)
                    acc[m][n] = __builtin_amdgcn_mfma_f32_16x16x32_bf16(af[m], bfr[n], acc[m][n], 0, 0, 0);
            __syncthreads();
        }

        bool offdiag = (C != R);

        float malf[4];
        #pragma unroll
        for (int n = 0; n < 4; ++n)
            malf[n] = (float)labels[bcol + wc * 64 + n * 16 + r16];
        float malr[16];
        #pragma unroll
        for (int m = 0; m < 4; ++m)
            #pragma unroll
            for (int r = 0; r < 4; ++r)
                malr[m * 4 + r] = (float)labels[brow + wr * 64 + m * 16 + hi * 4 + r];

        float cd[4] = {0.f, 0.f, 0.f, 0.f}, cn[4] = {0.f, 0.f, 0.f, 0.f};

        #pragma unroll
        for (int m = 0; m < 4; ++m) {
            #pragma unroll
            for (int r = 0; r < 4; ++r) {
                float pe = 0.f, pn = 0.f;
                #pragma unroll
                for (int n = 0; n < 4; ++n) {
                    float v  = acc[m][n][r];
                    float ex = __expf(v);
                    pe += ex;
                    pn += malf[n] * v;
                    cd[n] += ex;
                    cn[n] += malr[m * 4 + r] * v;
                }
                #pragma unroll
                for (int s = 1; s < 16; s <<= 1) {
                    pe += __shfl_xor(pe, s, 64);
                    pn += __shfl_xor(pn, s, 64);
                }
                if (r16 == 0) {
                    int rl = wr * 64 + m * 16 + hi * 4 + r;
                    rbuf[0][wc][rl] = pe;
                    rbuf[1][wc][rl] = pn;
                }
            }
        }

        if (offdiag) {
            #pragma unroll
            for (int n = 0; n < 4; ++n) {
                cd[n] += __shfl_xor(cd[n], 16, 64);
                cd[n] += __shfl_xor(cd[n], 32, 64);
                cn[n] += __shfl_xor(cn[n], 16, 64);
                cn[n] += __shfl_xor(cn[n], 32, 64);
                if (lane < 16) {
                    int cl = wc * 64 + n * 16 + lane;
                    cbuf[0][wr][cl] = cd[n];
                    cbuf[1][wr][cl] = cn[n];
                }
            }
        }
        __syncthreads();

        if (t < 128) {
            int i = brow + t;
            gden[(size_t)i * 32 + C] = rbuf[0][0][t] + rbuf[0][1][t];
            gnum[(size_t)i * 32 + C] = rbuf[1][0][t] + rbuf[1][1][t];
        } else if (offdiag) {
            int tt = t - 128;
            int j = bcol + tt;
            gden[(size_t)j * 32 + R] = cbuf[0][0][tt] + cbuf[0][1][tt];
            gnum[(size_t)j * 32 + R] = cbuf[1][0][tt] + cbuf[1][1][tt];
        }
    } else {
        // ================= simdiv path (register-direct, NT streaming) =================
        int sid = bid - bid / 3;            // 0..1055 over non-gemm bids
        if (sid >= BTOT / 4) return;
        int i = sid * 4 + w;                // one wave per row
        int g = lane >> 4, sub = lane & 15;

        const char* Eb = (const char*)(E + (size_t)i * DD);
        float4 e0 = *(const float4*)(Eb + 0 * 256 + sub * 16);
        float4 e1 = *(const float4*)(Eb + 1 * 256 + sub * 16);
        float4 e2 = *(const float4*)(Eb + 2 * 256 + sub * 16);
        float4 e3 = *(const float4*)(Eb + 3 * 256 + sub * 16);

        const char* Sb = (const char*)(Sim + (size_t)i * SS * DD) + g * 1024 + sub * 16;
        const char* Db = (const char*)(Div + (size_t)i * KKN * DD) + g * 1024 + sub * 16;

        float4 buf[4][4];
        float accs = 0.f, acce = 0.f;

#define ISSUE(SET)                                                                  \
    {                                                                               \
        const char* b_ = ((SET) < 8) ? (Sb + (SET) * 4096) : (Db + ((SET) - 8) * 4096); \
        buf[(SET) & 3][0] = ntload4(b_ + 0);                                        \
        buf[(SET) & 3][1] = ntload4(b_ + 256);                                      \
        buf[(SET) & 3][2] = ntload4(b_ + 512);                                      \
        buf[(SET) & 3][3] = ntload4(b_ + 768);                                      \
    }

#define COMPUTE(SET)                                                                \
    {                                                                               \
        float4 s0 = buf[(SET) & 3][0], s1 = buf[(SET) & 3][1];                      \
        float4 s2 = buf[(SET) & 3][2], s3 = buf[(SET) & 3][3];                      \
        float d = e0.x * s0.x + e0.y * s0.y + e0.z * s0.z + e0.w * s0.w             \
                + e1.x * s1.x + e1.y * s1.y + e1.z * s1.z + e1.w * s1.w             \
                + e2.x * s2.x + e2.y * s2.y + e2.z * s2.z + e2.w * s2.w             \
                + e3.x * s3.x + e3.y * s3.y + e3.z * s3.z + e3.w * s3.w;            \
        d += __shfl_xor(d, 1, 64);                                                  \
        d += __shfl_xor(d, 2, 64);                                                  \
        d += __shfl_xor(d, 4, 64);                                                  \
        d += __shfl_xor(d, 8, 64);                                                  \
        accs += d;                                                                  \
        acce += __expf(d);                                                          \
    }

        ISSUE(0) ISSUE(1) ISSUE(2) ISSUE(3)
        COMPUTE(0)  ISSUE(4)
        COMPUTE(1)  ISSUE(5)
        COMPUTE(2)  ISSUE(6)
        COMPUTE(3)  ISSUE(7)
        COMPUTE(4)  ISSUE(8)
        COMPUTE(5)  ISSUE(9)
        COMPUTE(6)  ISSUE(10)
        COMPUTE(7)  ISSUE(11)
        COMPUTE(8)  ISSUE(12)
        COMPUTE(9)  ISSUE(13)
        COMPUTE(10) ISSUE(14)
        COMPUTE(11) ISSUE(15)
        COMPUTE(12)
        COMPUTE(13)
        COMPUTE(14)
        COMPUTE(15)
#undef ISSUE
#undef COMPUTE

        accs += __shfl_xor(accs, 16, 64);
        accs += __shfl_xor(accs, 32, 64);
        acce += __shfl_xor(acce, 16, 64);
        acce += __shfl_xor(acce, 32, 64);

        // self-dot (bf16-rounded, matches MFMA diagonal)
        float sd = 0.f;
        {
            float c;
            c = bf2f(f2bf(e0.x)); sd += c * c;  c = bf2f(f2bf(e0.y)); sd += c * c;
            c = bf2f(f2bf(e0.z)); sd += c * c;  c = bf2f(f2bf(e0.w)); sd += c * c;
            c = bf2f(f2bf(e1.x)); sd += c * c;  c = bf2f(f2bf(e1.y)); sd += c * c;
            c = bf2f(f2bf(e1.z)); sd += c * c;  c = bf2f(f2bf(e1.w)); sd += c * c;
            c = bf2f(f2bf(e2.x)); sd += c * c;  c = bf2f(f2bf(e2.y)); sd += c * c;
            c = bf2f(f2bf(e2.z)); sd += c * c;  c = bf2f(f2bf(e2.w)); sd += c * c;
            c = bf2f(f2bf(e3.x)); sd += c * c;  c = bf2f(f2bf(e3.y)); sd += c * c;
            c = bf2f(f2bf(e3.z)); sd += c * c;  c = bf2f(f2bf(e3.w)); sd += c * c;
        }
        sd += __shfl_xor(sd, 1, 64);
        sd += __shfl_xor(sd, 2, 64);
        sd += __shfl_xor(sd, 4, 64);
        sd += __shfl_xor(sd, 8, 64);

        if (lane == 0) {
            float4 o; o.x = accs; o.y = acce; o.z = sd; o.w = 0.f;
            *(float4*)(sdpart + (size_t)i * 4) = o;
        }
    }
}

// ---- kernel 3: per-row fold (32 gemm partials + simdiv partials + self-term) ----
__global__ __launch_bounds__(128) void reduce1_kernel(
    const int* __restrict__ labels, const float* __restrict__ gden,
    const float* __restrict__ gnum, const float* __restrict__ sdpart,
    float* __restrict__ part)
{
    __shared__ float sA[128], sB[128];
    __shared__ int   sC[128];
    int p = blockIdx.x, t = threadIdx.x;
    int i = p * 128 + t;

    const float4* dr = reinterpret_cast<const float4*>(gden + (size_t)i * 32);
    const float4* nr = reinterpret_cast<const float4*>(gnum + (size_t)i * 32);
    float4 sp = *(const float4*)(sdpart + (size_t)i * 4);

    float num = sp.x;
    float den = sp.y;
    float sdv = sp.z;
    int lab = labels[i];
    den -= __expf(sdv);           // remove j==i from denominator
    num -= lab ? sdv : 0.f;       // remove j==i from numerator if mal[i]

    #pragma unroll
    for (int c = 0; c < 8; ++c) {
        float4 a = dr[c]; den += a.x + a.y + a.z + a.w;
        float4 b = nr[c]; num += b.x + b.y + b.z + b.w;
    }
    sA[t] = lab ? __logf(den) : 0.f;
    sB[t] = lab ? num : 0.f;
    sC[t] = lab;
    __syncthreads();
    for (int s = 64; s > 0; s >>= 1) {
        if (t < s) { sA[t] += sA[t + s]; sB[t] += sB[t + s]; sC[t] += sC[t + s]; }
        __syncthreads();
    }
    if (t == 0) {
        part[p]      = sA[0];
        part[32 + p] = sB[0];
        part[64 + p] = (float)sC[0];
    }
}

// ---- kernel 4: final scalar combine ----
__global__ __launch_bounds__(64) void final_kernel(const float* __restrict__ part,
                                                   float* __restrict__ out)
{
    int lane = threadIdx.x;
    float lg = (lane < 32) ? part[lane]      : 0.f;
    float nm = (lane < 32) ? part[32 + lane] : 0.f;
    float ml = (lane < 32) ? part[64 + lane] : 0.f;
    #pragma unroll
    for (int s = 1; s < 64; s <<= 1) {
        lg += __shfl_xor(lg, s, 64);
        nm += __shfl_xor(nm, s, 64);
        ml += __shfl_xor(ml, s, 64);
    }
    if (lane == 0) {
        float cnt = ml - 1.f + (float)(SS + KKN);
        out[0] = (lg - nm / cnt) / (float)BTOT;
    }
}

extern "C" void kernel_launch(void* const* d_in, const int* in_sizes, int n_in,
                              void* d_out, int out_size, void* d_ws, size_t ws_size,
                              hipStream_t stream) {
    const float* E   = (const float*)d_in[0];
    const float* Sim = (const float*)d_in[1];
    const float* Div = (const float*)d_in[2];
    const int* labels = (const int*)d_in[3];
    float* out = (float*)d_out;

    char* ws = (char*)d_ws;
    u16*   ebf    = (u16*)ws;   ws += (size_t)BTOT * DD * sizeof(u16);
    float* gden   = (float*)ws; ws += (size_t)BTOT * 32 * sizeof(float);
    float* gnum   = (float*)ws; ws += (size_t)BTOT * 32 * sizeof(float);
    float* sdpart = (float*)ws; ws += (size_t)BTOT * 4 * sizeof(float);
    float* part   = (float*)ws;

    cast_kernel<<<BTOT * DD / 8 / 256, 256, 0, stream>>>(E, ebf);
    fat_kernel<<<NBLK, 256, 0, stream>>>(E, Sim, Div, ebf, labels, gden, gnum, sdpart);
    reduce1_kernel<<<32, 128, 0, stream>>>(labels, gden, gnum, sdpart, part);
    final_kernel<<<1, 64, 0, stream>>>(part, out);
}

// Round 12
// 65.568 us; speedup vs baseline: 1.0325x; 1.0230x over previous
//
#include <hip/hip_runtime.h>
#include <stdint.h>

#define BTOT 4096
#define DD   256
#define SS   32
#define KKN  32
#define NGEMM 528              // 32*33/2 triangular tiles
#define NBLK  (NGEMM * 3)      // 1584: 1-in-3 gemm, rest simdiv (1056, 1024 used)

typedef unsigned short u16;
using f32x4  = __attribute__((ext_vector_type(4))) float;
using bf16x8 = __attribute__((ext_vector_type(8))) short;

__device__ __forceinline__ u16 f2bf(float f) {
    uint32_t u = __builtin_bit_cast(uint32_t, f);
    u = (u + 0x7FFFu + ((u >> 16) & 1u)) >> 16;
    return (u16)u;
}
__device__ __forceinline__ float bf2f(u16 h) {
    uint32_t u = ((uint32_t)h) << 16;
    return __builtin_bit_cast(float, u);
}

// ---- kernel 0: cast embeddings fp32 -> bf16 ----
__global__ __launch_bounds__(256) void cast_kernel(const float* __restrict__ E,
                                                   u16* __restrict__ ebf) {
    int idx = blockIdx.x * 256 + threadIdx.x;
    const float4* p = reinterpret_cast<const float4*>(E) + (size_t)idx * 2;
    float4 a = p[0], b = p[1];
    uint4 o;
    o.x = (uint32_t)f2bf(a.x) | ((uint32_t)f2bf(a.y) << 16);
    o.y = (uint32_t)f2bf(a.z) | ((uint32_t)f2bf(a.w) << 16);
    o.z = (uint32_t)f2bf(b.x) | ((uint32_t)f2bf(b.y) << 16);
    o.w = (uint32_t)f2bf(b.z) | ((uint32_t)f2bf(b.w) << 16);
    reinterpret_cast<uint4*>(ebf)[idx] = o;
}

// ---- fat kernel: bid%3==2 -> triangular GEMM tile; else -> simdiv rows ----
// simdiv path is LDS-free/register-direct, so gemm's 20KB static LDS no
// longer caps simdiv co-residency (round-5 failure mechanism removed).
__global__ __launch_bounds__(256) void fat_kernel(
    const float* __restrict__ E, const float* __restrict__ Sim, const float* __restrict__ Div,
    const u16* __restrict__ ebf, const int* __restrict__ labels,
    float* __restrict__ gden, float* __restrict__ gnum, float* __restrict__ sdpart)
{
    __shared__ u16 As[128 * 32];
    __shared__ u16 Bs[128 * 32];
    __shared__ float rbuf[2][2][128];
    __shared__ float cbuf[2][2][128];

    int bid  = blockIdx.x;
    int t    = threadIdx.x;
    int w    = t >> 6;
    int lane = t & 63;

    if (bid % 3 == 2) {
        // ================= GEMM path (round-4 verified body) =================
        int g = bid / 3;
        int R = (int)((65.0f - sqrtf(4225.0f - 8.0f * (float)g)) * 0.5f);
        while (R > 0 && R * (65 - R) / 2 > g) --R;
        while ((R + 1) * (64 - R) / 2 <= g) ++R;
        int C = R + (g - R * (65 - R) / 2);

        int brow = R * 128, bcol = C * 128;
        int wr = w >> 1, wc = w & 1;
        int r16 = lane & 15, hi = lane >> 4;
        int kq = hi * 8;

        f32x4 acc[4][4] = {};

        for (int kt = 0; kt < DD / 32; ++kt) {
            int k0 = kt * 32;
            #pragma unroll
            for (int it = 0; it < 2; ++it) {
                int c   = t + 256 * it;
                int row = c >> 2;
                int col = (c & 3) * 8;
                const u16* ga = &ebf[(size_t)(brow + row) * DD + k0 + col];
                const u16* gb = &ebf[(size_t)(bcol + row) * DD + k0 + col];
                __builtin_amdgcn_global_load_lds(
                    (const __attribute__((address_space(1))) unsigned int*)ga,
                    (__attribute__((address_space(3))) unsigned int*)&As[c * 8], 16, 0, 0);
                __builtin_amdgcn_global_load_lds(
                    (const __attribute__((address_space(1))) unsigned int*)gb,
                    (__attribute__((address_space(3))) unsigned int*)&Bs[c * 8], 16, 0, 0);
            }
            __syncthreads();

            bf16x8 af[4], bfr[4];
            #pragma unroll
            for (int m = 0; m < 4; ++m)
                af[m] = *(const bf16x8*)&As[(wr * 64 + m * 16 + r16) * 32 + kq];
            #pragma unroll
            for (int n = 0; n < 4; ++n)
                bfr[n] = *(const bf16x8*)&Bs[(wc * 64 + n * 16 + r16) * 32 + kq];
            #pragma unroll
            for (int m = 0; m < 4; ++m)
                #pragma unroll
                for (int n = 0; n < 4; ++n)
                    acc[m][n] = __builtin_amdgcn_mfma_f32_16x16x32_bf16(af[m], bfr[n], acc[m][n], 0, 0, 0);
            __syncthreads();
        }

        bool offdiag = (C != R);

        float malf[4];
        #pragma unroll
        for (int n = 0; n < 4; ++n)
            malf[n] = (float)labels[bcol + wc * 64 + n * 16 + r16];
        float malr[16];
        #pragma unroll
        for (int m = 0; m < 4; ++m)
            #pragma unroll
            for (int r = 0; r < 4; ++r)
                malr[m * 4 + r] = (float)labels[brow + wr * 64 + m * 16 + hi * 4 + r];

        float cd[4] = {0.f, 0.f, 0.f, 0.f}, cn[4] = {0.f, 0.f, 0.f, 0.f};

        #pragma unroll
        for (int m = 0; m < 4; ++m) {
            #pragma unroll
            for (int r = 0; r < 4; ++r) {
                float pe = 0.f, pn = 0.f;
                #pragma unroll
                for (int n = 0; n < 4; ++n) {
                    float v  = acc[m][n][r];
                    float ex = __expf(v);
                    pe += ex;
                    pn += malf[n] * v;
                    cd[n] += ex;
                    cn[n] += malr[m * 4 + r] * v;
                }
                #pragma unroll
                for (int s = 1; s < 16; s <<= 1) {
                    pe += __shfl_xor(pe, s, 64);
                    pn += __shfl_xor(pn, s, 64);
                }
                if (r16 == 0) {
                    int rl = wr * 64 + m * 16 + hi * 4 + r;
                    rbuf[0][wc][rl] = pe;
                    rbuf[1][wc][rl] = pn;
                }
            }
        }

        if (offdiag) {
            #pragma unroll
            for (int n = 0; n < 4; ++n) {
                cd[n] += __shfl_xor(cd[n], 16, 64);
                cd[n] += __shfl_xor(cd[n], 32, 64);
                cn[n] += __shfl_xor(cn[n], 16, 64);
                cn[n] += __shfl_xor(cn[n], 32, 64);
                if (lane < 16) {
                    int cl = wc * 64 + n * 16 + lane;
                    cbuf[0][wr][cl] = cd[n];
                    cbuf[1][wr][cl] = cn[n];
                }
            }
        }
        __syncthreads();

        if (t < 128) {
            int i = brow + t;
            gden[(size_t)i * 32 + C] = rbuf[0][0][t] + rbuf[0][1][t];
            gnum[(size_t)i * 32 + C] = rbuf[1][0][t] + rbuf[1][1][t];
        } else if (offdiag) {
            int tt = t - 128;
            int j = bcol + tt;
            gden[(size_t)j * 32 + R] = cbuf[0][0][tt] + cbuf[0][1][tt];
            gnum[(size_t)j * 32 + R] = cbuf[1][0][tt] + cbuf[1][1][tt];
        }
    } else {
        // ================= simdiv path (round-7 register-direct) =================
        int sid = bid - bid / 3;            // 0..1055 over non-gemm bids
        if (sid >= BTOT / 4) return;
        int i = sid * 4 + w;                // one wave per row
        int g = lane >> 4, sub = lane & 15;

        const char* Eb = (const char*)(E + (size_t)i * DD);
        float4 e0 = *(const float4*)(Eb + 0 * 256 + sub * 16);
        float4 e1 = *(const float4*)(Eb + 1 * 256 + sub * 16);
        float4 e2 = *(const float4*)(Eb + 2 * 256 + sub * 16);
        float4 e3 = *(const float4*)(Eb + 3 * 256 + sub * 16);

        const char* Sb = (const char*)(Sim + (size_t)i * SS * DD) + g * 1024 + sub * 16;
        const char* Db = (const char*)(Div + (size_t)i * KKN * DD) + g * 1024 + sub * 16;

        float4 buf[4][4];
        float accs = 0.f, acce = 0.f;

#define ISSUE(SET)                                                                  \
    {                                                                               \
        const char* b_ = ((SET) < 8) ? (Sb + (SET) * 4096) : (Db + ((SET) - 8) * 4096); \
        buf[(SET) & 3][0] = *(const float4*)(b_ + 0);                               \
        buf[(SET) & 3][1] = *(const float4*)(b_ + 256);                             \
        buf[(SET) & 3][2] = *(const float4*)(b_ + 512);                             \
        buf[(SET) & 3][3] = *(const float4*)(b_ + 768);                             \
    }

#define COMPUTE(SET)                                                                \
    {                                                                               \
        float4 s0 = buf[(SET) & 3][0], s1 = buf[(SET) & 3][1];                      \
        float4 s2 = buf[(SET) & 3][2], s3 = buf[(SET) & 3][3];                      \
        float d = e0.x * s0.x + e0.y * s0.y + e0.z * s0.z + e0.w * s0.w             \
                + e1.x * s1.x + e1.y * s1.y + e1.z * s1.z + e1.w * s1.w             \
                + e2.x * s2.x + e2.y * s2.y + e2.z * s2.z + e2.w * s2.w             \
                + e3.x * s3.x + e3.y * s3.y + e3.z * s3.z + e3.w * s3.w;            \
        d += __shfl_xor(d, 1, 64);                                                  \
        d += __shfl_xor(d, 2, 64);                                                  \
        d += __shfl_xor(d, 4, 64);                                                  \
        d += __shfl_xor(d, 8, 64);                                                  \
        accs += d;                                                                  \
        acce += __expf(d);                                                          \
    }

        ISSUE(0) ISSUE(1) ISSUE(2) ISSUE(3)
        COMPUTE(0)  ISSUE(4)
        COMPUTE(1)  ISSUE(5)
        COMPUTE(2)  ISSUE(6)
        COMPUTE(3)  ISSUE(7)
        COMPUTE(4)  ISSUE(8)
        COMPUTE(5)  ISSUE(9)
        COMPUTE(6)  ISSUE(10)
        COMPUTE(7)  ISSUE(11)
        COMPUTE(8)  ISSUE(12)
        COMPUTE(9)  ISSUE(13)
        COMPUTE(10) ISSUE(14)
        COMPUTE(11) ISSUE(15)
        COMPUTE(12)
        COMPUTE(13)
        COMPUTE(14)
        COMPUTE(15)
#undef ISSUE
#undef COMPUTE

        accs += __shfl_xor(accs, 16, 64);
        accs += __shfl_xor(accs, 32, 64);
        acce += __shfl_xor(acce, 16, 64);
        acce += __shfl_xor(acce, 32, 64);

        // self-dot (bf16-rounded, matches MFMA diagonal)
        float sd = 0.f;
        {
            float c;
            c = bf2f(f2bf(e0.x)); sd += c * c;  c = bf2f(f2bf(e0.y)); sd += c * c;
            c = bf2f(f2bf(e0.z)); sd += c * c;  c = bf2f(f2bf(e0.w)); sd += c * c;
            c = bf2f(f2bf(e1.x)); sd += c * c;  c = bf2f(f2bf(e1.y)); sd += c * c;
            c = bf2f(f2bf(e1.z)); sd += c * c;  c = bf2f(f2bf(e1.w)); sd += c * c;
            c = bf2f(f2bf(e2.x)); sd += c * c;  c = bf2f(f2bf(e2.y)); sd += c * c;
            c = bf2f(f2bf(e2.z)); sd += c * c;  c = bf2f(f2bf(e2.w)); sd += c * c;
            c = bf2f(f2bf(e3.x)); sd += c * c;  c = bf2f(f2bf(e3.y)); sd += c * c;
            c = bf2f(f2bf(e3.z)); sd += c * c;  c = bf2f(f2bf(e3.w)); sd += c * c;
        }
        sd += __shfl_xor(sd, 1, 64);
        sd += __shfl_xor(sd, 2, 64);
        sd += __shfl_xor(sd, 4, 64);
        sd += __shfl_xor(sd, 8, 64);

        if (lane == 0) {
            float4 o; o.x = accs; o.y = acce; o.z = sd; o.w = 0.f;
            *(float4*)(sdpart + (size_t)i * 4) = o;
        }
    }
}

// ---- kernel 3: per-row fold (32 gemm partials + simdiv partials + self-term) ----
__global__ __launch_bounds__(128) void reduce1_kernel(
    const int* __restrict__ labels, const float* __restrict__ gden,
    const float* __restrict__ gnum, const float* __restrict__ sdpart,
    float* __restrict__ part)
{
    __shared__ float sA[128], sB[128];
    __shared__ int   sC[128];
    int p = blockIdx.x, t = threadIdx.x;
    int i = p * 128 + t;

    const float4* dr = reinterpret_cast<const float4*>(gden + (size_t)i * 32);
    const float4* nr = reinterpret_cast<const float4*>(gnum + (size_t)i * 32);
    float4 sp = *(const float4*)(sdpart + (size_t)i * 4);

    float num = sp.x;
    float den = sp.y;
    float sdv = sp.z;
    int lab = labels[i];
    den -= __expf(sdv);           // remove j==i from denominator
    num -= lab ? sdv : 0.f;       // remove j==i from numerator if mal[i]

    #pragma unroll
    for (int c = 0; c < 8; ++c) {
        float4 a = dr[c]; den += a.x + a.y + a.z + a.w;
        float4 b = nr[c]; num += b.x + b.y + b.z + b.w;
    }
    sA[t] = lab ? __logf(den) : 0.f;
    sB[t] = lab ? num : 0.f;
    sC[t] = lab;
    __syncthreads();
    for (int s = 64; s > 0; s >>= 1) {
        if (t < s) { sA[t] += sA[t + s]; sB[t] += sB[t + s]; sC[t] += sC[t + s]; }
        __syncthreads();
    }
    if (t == 0) {
        part[p]      = sA[0];
        part[32 + p] = sB[0];
        part[64 + p] = (float)sC[0];
    }
}

// ---- kernel 4: final scalar combine ----
__global__ __launch_bounds__(64) void final_kernel(const float* __restrict__ part,
                                                   float* __restrict__ out)
{
    int lane = threadIdx.x;
    float lg = (lane < 32) ? part[lane]      : 0.f;
    float nm = (lane < 32) ? part[32 + lane] : 0.f;
    float ml = (lane < 32) ? part[64 + lane] : 0.f;
    #pragma unroll
    for (int s = 1; s < 64; s <<= 1) {
        lg += __shfl_xor(lg, s, 64);
        nm += __shfl_xor(nm, s, 64);
        ml += __shfl_xor(ml, s, 64);
    }
    if (lane == 0) {
        float cnt = ml - 1.f + (float)(SS + KKN);
        out[0] = (lg - nm / cnt) / (float)BTOT;
    }
}

extern "C" void kernel_launch(void* const* d_in, const int* in_sizes, int n_in,
                              void* d_out, int out_size, void* d_ws, size_t ws_size,
                              hipStream_t stream) {
    const float* E   = (const float*)d_in[0];
    const float* Sim = (const float*)d_in[1];
    const float* Div = (const float*)d_in[2];
    const int* labels = (const int*)d_in[3];
    float* out = (float*)d_out;

    char* ws = (char*)d_ws;
    u16*   ebf    = (u16*)ws;   ws += (size_t)BTOT * DD * sizeof(u16);
    float* gden   = (float*)ws; ws += (size_t)BTOT * 32 * sizeof(float);
    float* gnum   = (float*)ws; ws += (size_t)BTOT * 32 * sizeof(float);
    float* sdpart = (float*)ws; ws += (size_t)BTOT * 4 * sizeof(float);
    float* part   = (float*)ws;

    cast_kernel<<<BTOT * DD / 8 / 256, 256, 0, stream>>>(E, ebf);
    fat_kernel<<<NBLK, 256, 0, stream>>>(E, Sim, Div, ebf, labels, gden, gnum, sdpart);
    reduce1_kernel<<<32, 128, 0, stream>>>(labels, gden, gnum, sdpart, part);
    final_kernel<<<1, 64, 0, stream>>>(part, out);
}